// Round 1
// baseline (240.641 us; speedup 1.0000x reference)
//
#include <hip/hip_runtime.h>

// SubPixelUpscaling (pixel shuffle), r=2.
// in : (B=8, H=256, W=256, Cin=256) f32, NHWC
// out: (B=8, OH=512, OW=512, Cout=64) f32, NHWC
// out[n, 2h+r1, 2w+r2, c] = in[n, h, w, 4c + 2*r1 + r2]
//
// One thread per (n,h,w,c). float4 load of in[..., 4c..4c+3] yields the 4
// output values for (r1,r2) in {0,1}^2. Reads: 16B/lane fully coalesced.
// Writes: 4 stores, each coalesced across the wave into a 256B segment.

__global__ __launch_bounds__(256) void SubPixelUpscaling_kernel(
    const float* __restrict__ in, float* __restrict__ out, int total) {
    const int stride = gridDim.x * blockDim.x;
    for (int tid = blockIdx.x * blockDim.x + threadIdx.x; tid < total; tid += stride) {
        const int c   = tid & 63;          // output channel
        const int pix = tid >> 6;          // n*H*W + h*W + w
        const int w   = pix & 255;
        const int h   = (pix >> 8) & 255;
        const int n   = pix >> 16;

        // input float4 at ((n*H + h)*W + w)*256 + 4c
        const float4 v = *reinterpret_cast<const float4*>(in + (pix << 8) + (c << 2));

        // output base: ((n*512 + 2h)*512 + 2w)*64 + c
        const int base = (((n << 9) + (h << 1)) << 9 | (w << 1)) << 6 | c;

        out[base]               = v.x;  // (2h,   2w  )
        out[base + 64]          = v.y;  // (2h,   2w+1)
        out[base + 32768]       = v.z;  // (2h+1, 2w  )
        out[base + 32768 + 64]  = v.w;  // (2h+1, 2w+1)
    }
}

extern "C" void kernel_launch(void* const* d_in, const int* in_sizes, int n_in,
                              void* d_out, int out_size, void* d_ws, size_t ws_size,
                              hipStream_t stream) {
    const float* in = (const float*)d_in[0];
    float* out = (float*)d_out;

    // total threads = B*H*W*Cout = out_size = 134,217,728 / ... one per output-channel group
    const int total = out_size / 4;  // each thread produces 4 outputs
    const int block = 256;
    const int grid = 2048;  // grid-stride; memory-bound cap

    SubPixelUpscaling_kernel<<<grid, block, 0, stream>>>(in, out, total);
}

// Round 2
// 227.306 us; speedup vs baseline: 1.0587x; 1.0587x over previous
//
#include <hip/hip_runtime.h>

// SubPixelUpscaling (pixel shuffle), r=2.
// in : (B=8, H=256, W=256, Cin=256) f32, NHWC
// out: (B=8, OH=512, OW=512, Cout=64) f32, NHWC
// out[n, 2h+r1, 2w+r2, c] = in[n, h, w, 4c + 2*r1 + r2]
//
// Lane c (tid&63) loads float4 v = in[pix, 4c..4c+3] = the 4 (r1,r2) values
// for output channel c. A 4x4 transpose across each lane-quad (shfl_xor 1,2)
// rearranges so lane with s=(c&3) holds channels (c&~3)..(c&~3)+3 for that
// (r1,r2) -> ONE float4 store per thread, full-cache-line write segments.

__global__ __launch_bounds__(256) void SubPixelUpscaling_kernel(
    const float* __restrict__ in, float* __restrict__ out, int total) {
    const int stride = gridDim.x * blockDim.x;
    for (int tid = blockIdx.x * blockDim.x + threadIdx.x; tid < total; tid += stride) {
        const int c   = tid & 63;          // output channel (lane)
        const int pix = tid >> 6;          // n*H*W + h*W + w
        const int w   = pix & 255;
        const int h   = (pix >> 8) & 255;
        const int n   = pix >> 16;

        // coalesced: lane c loads 16B at pix*1KB + c*16B (1KB per wave instr)
        const float4 v = *reinterpret_cast<const float4*>(in + (pix << 8) + (c << 2));

        // ---- 4x4 transpose within each quad of lanes ----
        // lane i (i=c&3) holds v[j] = value(channel 4q+i, s=j); after:
        // lane i holds w[k] = value(channel 4q+k, s=i)
        const bool p1 = (c & 1) != 0;
        const bool p2 = (c & 2) != 0;

        float a = p1 ? v.x : v.y;
        float b = p1 ? v.z : v.w;
        float ra = __shfl_xor(a, 1);
        float rb = __shfl_xor(b, 1);
        float u0 = p1 ? ra  : v.x;
        float u1 = p1 ? v.y : ra;
        float u2 = p1 ? rb  : v.z;
        float u3 = p1 ? v.w : rb;

        float cc = p2 ? u0 : u2;
        float dd = p2 ? u1 : u3;
        float rc = __shfl_xor(cc, 2);
        float rd = __shfl_xor(dd, 2);
        float4 wv;
        wv.x = p2 ? rc : u0;
        wv.y = p2 ? rd : u1;
        wv.z = p2 ? u2 : rc;
        wv.w = p2 ? u3 : rd;

        // ---- one float4 store: channels cb..cb+3 at (2h+r1, 2w+r2) ----
        const int s  = c & 3;              // s = 2*r1 + r2
        const int r1 = s >> 1;
        const int r2 = s & 1;
        const int cb = c & ~3;             // channel base, 16B aligned
        const int obase = ((((n << 9) + (h << 1) + r1) << 9) | ((w << 1) + r2)) << 6 | cb;

        *reinterpret_cast<float4*>(out + obase) = wv;
    }
}

extern "C" void kernel_launch(void* const* d_in, const int* in_sizes, int n_in,
                              void* d_out, int out_size, void* d_ws, size_t ws_size,
                              hipStream_t stream) {
    const float* in = (const float*)d_in[0];
    float* out = (float*)d_out;

    const int total = out_size / 4;  // one thread per 4 output elements
    const int block = 256;
    const int grid  = 2048;          // 8 blocks/CU -> 32 waves/CU, grid-stride

    SubPixelUpscaling_kernel<<<grid, block, 0, stream>>>(in, out, total);
}